// Round 1
// baseline (57.795 us; speedup 1.0000x reference)
//
#include <hip/hip_runtime.h>

#define B_  1024
#define I_  512
#define O_  512
#define E_  16
#define K_  8192   // E_*I_ flattened contraction axis

#define KSPLIT 8
#define KRANGE (K_ / KSPLIT)   // 1024
#define BK 64
#define NSTEP (KRANGE / BK)    // 16

typedef __attribute__((ext_vector_type(8))) short short8;
typedef __attribute__((ext_vector_type(8))) unsigned short ushort8;
typedef __attribute__((ext_vector_type(4))) float f32x4;

__device__ __forceinline__ unsigned short f2bf(float f) {
  union { float f; unsigned u; } v; v.f = f;
  unsigned r = v.u + 0x7fffu + ((v.u >> 16) & 1u);
  return (unsigned short)(r >> 16);
}

__device__ __forceinline__ void gload_lds16(const unsigned short* g, unsigned short* l) {
  __builtin_amdgcn_global_load_lds(
      (const __attribute__((address_space(1))) void*)g,
      (__attribute__((address_space(3))) void*)l, 16, 0, 0);
}

// A[b][e*512+i] = bf16(coeffs[b][e] * x[b][i]); 8 elems per thread
__global__ void prep_a_kernel(const float* __restrict__ x,
                              const float* __restrict__ coeffs,
                              unsigned short* __restrict__ A) {
  int t = blockIdx.x * 256 + threadIdx.x;
  int base = t * 8;
  int b = base >> 13;            // /8192
  int rem = base & (K_ - 1);
  int e = rem >> 9;              // /512
  int i0 = rem & (I_ - 1);
  float c = coeffs[b * E_ + e];
  const float4* xp = (const float4*)(x + b * I_ + i0);
  float4 v0 = xp[0], v1 = xp[1];
  ushort8 r;
  r[0] = f2bf(v0.x * c); r[1] = f2bf(v0.y * c);
  r[2] = f2bf(v0.z * c); r[3] = f2bf(v0.w * c);
  r[4] = f2bf(v1.x * c); r[5] = f2bf(v1.y * c);
  r[6] = f2bf(v1.z * c); r[7] = f2bf(v1.w * c);
  *(ushort8*)(A + base) = r;
}

// Wt[o][e*512+i] = bf16(W[e][i][o])   (transpose + cast, LDS-tiled 64x64)
__global__ void prep_w_kernel(const float* __restrict__ W,
                              unsigned short* __restrict__ Wt) {
  __shared__ unsigned short tile[64][65];
  int kt = blockIdx.x * 64;   // along K (8192/64 = 128)
  int nt = blockIdx.y * 64;   // along O (512/64 = 8)
  int t = threadIdx.x;
#pragma unroll
  for (int it = 0; it < 16; ++it) {
    int idx = it * 256 + t;
    int r = idx >> 6, c = idx & 63;
    tile[r][c] = f2bf(W[(long)(kt + r) * O_ + nt + c]);
  }
  __syncthreads();
#pragma unroll
  for (int it = 0; it < 2; ++it) {
    int idx = it * 256 + t;       // 0..511
    int r2 = idx >> 3;            // o-row within tile 0..63
    int c2 = (idx & 7) * 8;       // k base within tile
    ushort8 v;
#pragma unroll
    for (int j = 0; j < 8; ++j) v[j] = tile[c2 + j][r2];
    *(ushort8*)(Wt + (long)(nt + r2) * K_ + kt + c2) = v;
  }
}

// out[b][o] = sum_e coeffs[b][e] * bias[e][o]  (also zero-initializes out for the atomics)
__global__ void bias_init_kernel(const float* __restrict__ coeffs,
                                 const float* __restrict__ eb,
                                 float* __restrict__ out) {
  int t = blockIdx.x * 256 + threadIdx.x;   // 131072 threads, 4 outputs each
  int b = t >> 7;
  int o4 = (t & 127) * 4;
  const float* cb = coeffs + b * E_;
  float4 acc = {0.f, 0.f, 0.f, 0.f};
#pragma unroll
  for (int e = 0; e < E_; ++e) {
    float c = cb[e];
    float4 bv = *(const float4*)(eb + e * O_ + o4);
    acc.x += c * bv.x; acc.y += c * bv.y; acc.z += c * bv.z; acc.w += c * bv.w;
  }
  *(float4*)(out + b * O_ + o4) = acc;
}

// C[1024][512] += A[1024][8192] @ Wt^T  (Wt stored [N][K]); 128x128 tile, split-K=8
__global__ __launch_bounds__(256) void gemm_kernel(
    const unsigned short* __restrict__ A,
    const unsigned short* __restrict__ Wt,
    float* __restrict__ out) {
  __shared__ unsigned short As[128 * 64];   // [row][k]  64 bf16/row
  __shared__ unsigned short Bs[128 * 64];   // [col(n)][k]
  int bx = blockIdx.x;
  int ks = bx & (KSPLIT - 1);
  int tile = bx >> 3;
  int tm = tile >> 2, tn = tile & 3;
  int brow = tm * 128, bcol = tn * 128;
  long k0 = (long)ks * KRANGE;

  int tid = threadIdx.x;
  int lane = tid & 63, wave = tid >> 6;
  int wr = wave >> 1, wc = wave & 1;

  f32x4 acc[4][4];
#pragma unroll
  for (int m = 0; m < 4; ++m)
#pragma unroll
    for (int n = 0; n < 4; ++n) acc[m][n] = (f32x4){0.f, 0.f, 0.f, 0.f};

  int lr8 = lane >> 3;          // staging: lane covers row lr8 within 8-row chunk
  int lc8 = (lane & 7) * 8;     // col elem base (8 bf16 = 16B)
  const unsigned short* gA = A  + (long)(brow + lr8) * K_ + k0 + lc8;
  const unsigned short* gB = Wt + (long)(bcol + lr8) * K_ + k0 + lc8;

  for (int s = 0; s < NSTEP; ++s) {
    long kof = (long)s * BK;
#pragma unroll
    for (int i = 0; i < 4; ++i) {
      int chunk = i * 4 + wave;   // 0..15, wave-uniform LDS base
      gload_lds16(gA + (long)chunk * 8 * K_ + kof, As + chunk * 512);
      gload_lds16(gB + (long)chunk * 8 * K_ + kof, Bs + chunk * 512);
    }
    __syncthreads();   // compiler drains vmcnt(0) before s_barrier
#pragma unroll
    for (int kk = 0; kk < 2; ++kk) {
      int klo = kk * 32 + (lane >> 4) * 8;
      short8 af[4], bfr[4];
#pragma unroll
      for (int m = 0; m < 4; ++m)
        af[m] = *(const short8*)(As + (wr * 64 + m * 16 + (lane & 15)) * 64 + klo);
#pragma unroll
      for (int n = 0; n < 4; ++n)
        bfr[n] = *(const short8*)(Bs + (wc * 64 + n * 16 + (lane & 15)) * 64 + klo);
#pragma unroll
      for (int m = 0; m < 4; ++m)
#pragma unroll
        for (int n = 0; n < 4; ++n)
          acc[m][n] = __builtin_amdgcn_mfma_f32_16x16x32_bf16(af[m], bfr[n], acc[m][n], 0, 0, 0);
    }
    __syncthreads();
  }

  // C/D layout: col = lane&15, row = (lane>>4)*4 + reg  (m89/m91 verified)
  int crow = wr * 64 + (lane >> 4) * 4;
  int ccol = wc * 64 + (lane & 15);
#pragma unroll
  for (int m = 0; m < 4; ++m)
#pragma unroll
    for (int n = 0; n < 4; ++n) {
      float* p = out + (long)(brow + crow + m * 16) * O_ + bcol + ccol + n * 16;
#pragma unroll
      for (int j = 0; j < 4; ++j)
        atomicAdd(p + (long)j * O_, acc[m][n][j]);
    }
}

extern "C" void kernel_launch(void* const* d_in, const int* in_sizes, int n_in,
                              void* d_out, int out_size, void* d_ws, size_t ws_size,
                              hipStream_t stream) {
  const float* x      = (const float*)d_in[0];
  const float* coeffs = (const float*)d_in[1];
  const float* W      = (const float*)d_in[2];
  const float* eb     = (const float*)d_in[3];
  float* out = (float*)d_out;

  unsigned short* A  = (unsigned short*)d_ws;                               // 16 MiB
  unsigned short* Wt = (unsigned short*)((char*)d_ws + (size_t)B_ * K_ * 2); // 8 MiB

  prep_a_kernel<<<dim3(B_ * K_ / 8 / 256), 256, 0, stream>>>(x, coeffs, A);
  prep_w_kernel<<<dim3(K_ / 64, O_ / 64), 256, 0, stream>>>(W, Wt);
  bias_init_kernel<<<dim3(B_ * O_ / 4 / 256), 256, 0, stream>>>(coeffs, eb, out);
  gemm_kernel<<<dim3(32 * KSPLIT), 256, 0, stream>>>(A, Wt, out);
}

// Round 2
// 34.055 us; speedup vs baseline: 1.6971x; 1.6971x over previous
//
#include <hip/hip_runtime.h>

#define B_  1024
#define I_  512
#define O_  512
#define E_  16
#define K_  8192   // E_*I_ flattened contraction axis

#define KSPLIT 16
#define KRANGE (K_ / KSPLIT)   // 512
#define BK 64
#define NSTEP (KRANGE / BK)    // 8
#define NTILE 32               // (1024/128)*(512/128)

typedef __attribute__((ext_vector_type(8))) short short8;
typedef __attribute__((ext_vector_type(8))) unsigned short ushort8;
typedef __attribute__((ext_vector_type(4))) unsigned short ushort4v;
typedef __attribute__((ext_vector_type(4))) float f32x4;

__device__ __forceinline__ unsigned short f2bf(float f) {
  union { float f; unsigned u; } v; v.f = f;
  unsigned r = v.u + 0x7fffu + ((v.u >> 16) & 1u);
  return (unsigned short)(r >> 16);
}
__device__ __forceinline__ float bf2f(unsigned short h) {
  union { unsigned u; float f; } v; v.u = ((unsigned)h) << 16;
  return v.f;
}

__device__ __forceinline__ void gload_lds16(const unsigned short* g, unsigned short* l) {
  __builtin_amdgcn_global_load_lds(
      (const __attribute__((address_space(1))) void*)g,
      (__attribute__((address_space(3))) void*)l, 16, 0, 0);
}

// Fused prep: blocks [0,4096) build A[b][e*512+i] = bf16(c[b,e]*x[b,i]);
// blocks [4096,5120) build Wt[o][e*512+i] = bf16(W[e][i][o]) via LDS transpose.
__global__ void prep_kernel(const float* __restrict__ x,
                            const float* __restrict__ coeffs,
                            const float* __restrict__ W,
                            unsigned short* __restrict__ A,
                            unsigned short* __restrict__ Wt) {
  __shared__ unsigned short tile[64][65];
  if (blockIdx.x < 4096) {
    int t = blockIdx.x * 256 + threadIdx.x;
    int base = t * 8;
    int b = base >> 13;
    int rem = base & (K_ - 1);
    int e = rem >> 9;
    int i0 = rem & (I_ - 1);
    float c = coeffs[b * E_ + e];
    const float4* xp = (const float4*)(x + b * I_ + i0);
    float4 v0 = xp[0], v1 = xp[1];
    ushort8 r;
    r[0] = f2bf(v0.x * c); r[1] = f2bf(v0.y * c);
    r[2] = f2bf(v0.z * c); r[3] = f2bf(v0.w * c);
    r[4] = f2bf(v1.x * c); r[5] = f2bf(v1.y * c);
    r[6] = f2bf(v1.z * c); r[7] = f2bf(v1.w * c);
    *(ushort8*)(A + base) = r;
  } else {
    int bw = blockIdx.x - 4096;
    int kt = (bw & 127) << 6;   // along K
    int nt = (bw >> 7) << 6;    // along O
    int t = threadIdx.x;
#pragma unroll
    for (int it = 0; it < 16; ++it) {
      int idx = it * 256 + t;
      int r = idx >> 6, c = idx & 63;
      tile[r][c] = f2bf(W[(long)(kt + r) * O_ + nt + c]);
    }
    __syncthreads();
#pragma unroll
    for (int it = 0; it < 2; ++it) {
      int idx = it * 256 + t;
      int r2 = idx >> 3;
      int c2 = (idx & 7) * 8;
      ushort8 v;
#pragma unroll
      for (int j = 0; j < 8; ++j) v[j] = tile[c2 + j][r2];
      *(ushort8*)(Wt + (long)(nt + r2) * K_ + kt + c2) = v;
    }
  }
}

// fallback-mode bias init (atomic path)
__global__ void bias_init_kernel(const float* __restrict__ coeffs,
                                 const float* __restrict__ eb,
                                 float* __restrict__ out) {
  int t = blockIdx.x * 256 + threadIdx.x;
  int b = t >> 7;
  int o4 = (t & 127) * 4;
  const float* cb = coeffs + b * E_;
  float4 acc = {0.f, 0.f, 0.f, 0.f};
#pragma unroll
  for (int e = 0; e < E_; ++e) {
    float c = cb[e];
    float4 bv = *(const float4*)(eb + e * O_ + o4);
    acc.x += c * bv.x; acc.y += c * bv.y; acc.z += c * bv.z; acc.w += c * bv.w;
  }
  *(float4*)(out + b * O_ + o4) = acc;
}

// 128x128 tile, BK=64, split-K=16, double-buffered LDS, 2-phase pipeline,
// T2 XOR-swizzle (pre-swizzled global source + swizzled ds_read).
template <int USE_PART>
__global__ __launch_bounds__(256) void gemm_kernel(
    const unsigned short* __restrict__ A,
    const unsigned short* __restrict__ Wt,
    float* __restrict__ out,
    unsigned short* __restrict__ part) {
  __shared__ unsigned short As[2][128 * 64];
  __shared__ unsigned short Bs[2][128 * 64];
  int bx = blockIdx.x;
  int ks = bx & (KSPLIT - 1);
  int tile = bx >> 4;
  int tm = tile >> 2, tn = tile & 3;
  int brow = tm * 128, bcol = tn * 128;
  long k0 = (long)ks * KRANGE;

  int tid = threadIdx.x;
  int lane = tid & 63, wave = tid >> 6;
  int wr = wave >> 1, wc = wave & 1;

  f32x4 acc[4][4];
#pragma unroll
  for (int m = 0; m < 4; ++m)
#pragma unroll
    for (int n = 0; n < 4; ++n) acc[m][n] = (f32x4){0.f, 0.f, 0.f, 0.f};

  // staging source: row-within-chunk = lane>>3 (== row&7), 16B piece j = lane&7.
  // Pre-swizzle k so LDS ends up holding elem k at byte (k*2 ^ ((row&7)<<4)).
  int lr8 = lane >> 3;
  int jj = lane & 7;
  int ksrc = (jj ^ lr8) * 8;
  const unsigned short* gA = A + (long)(brow + lr8) * K_ + k0 + ksrc;
  const unsigned short* gB = Wt + (long)(bcol + lr8) * K_ + k0 + ksrc;

  auto STAGE = [&](int buf, int s) {
    long kof = (long)s * BK;
#pragma unroll
    for (int i = 0; i < 4; ++i) {
      int chunk = i * 4 + wave;  // wave-uniform LDS base
      gload_lds16(gA + (long)chunk * 8 * K_ + kof, &As[buf][chunk * 512]);
      gload_lds16(gB + (long)chunk * 8 * K_ + kof, &Bs[buf][chunk * 512]);
    }
  };

  auto COMPUTE = [&](int buf) {
#pragma unroll
    for (int kk = 0; kk < 2; ++kk) {
      int kbyte = kk * 64 + (lane >> 4) * 16;  // byte offset of 8 bf16 along K
      short8 af[4], bfr[4];
#pragma unroll
      for (int m = 0; m < 4; ++m) {
        int r = wr * 64 + m * 16 + (lane & 15);
        int off = r * 64 + ((kbyte ^ ((r & 7) << 4)) >> 1);
        af[m] = *(const short8*)(&As[buf][off]);
      }
#pragma unroll
      for (int n = 0; n < 4; ++n) {
        int r = wc * 64 + n * 16 + (lane & 15);
        int off = r * 64 + ((kbyte ^ ((r & 7) << 4)) >> 1);
        bfr[n] = *(const short8*)(&Bs[buf][off]);
      }
#pragma unroll
      for (int m = 0; m < 4; ++m)
#pragma unroll
        for (int n = 0; n < 4; ++n)
          acc[m][n] = __builtin_amdgcn_mfma_f32_16x16x32_bf16(af[m], bfr[n], acc[m][n], 0, 0, 0);
    }
  };

  STAGE(0, 0);
  __syncthreads();
#pragma unroll
  for (int s = 0; s < NSTEP; ++s) {
    if (s + 1 < NSTEP) STAGE((s + 1) & 1, s + 1);  // prefetch BEFORE compute
    COMPUTE(s & 1);
    __syncthreads();
  }

  // C/D layout: col = lane&15, row = (lane>>4)*4 + reg
  int crow = wr * 64 + (lane >> 4) * 4;
  int ccol = wc * 64 + (lane & 15);
  if (USE_PART) {
    unsigned short* pb = part + (long)ks * B_ * O_;
#pragma unroll
    for (int m = 0; m < 4; ++m)
#pragma unroll
      for (int n = 0; n < 4; ++n) {
        long rbase = (long)(brow + crow + m * 16) * O_ + bcol + ccol + n * 16;
#pragma unroll
        for (int j = 0; j < 4; ++j)
          pb[rbase + (long)j * O_] = f2bf(acc[m][n][j]);
      }
  } else {
#pragma unroll
    for (int m = 0; m < 4; ++m)
#pragma unroll
      for (int n = 0; n < 4; ++n) {
        float* p = out + (long)(brow + crow + m * 16) * O_ + bcol + ccol + n * 16;
#pragma unroll
        for (int j = 0; j < 4; ++j)
          atomicAdd(p + (long)j * O_, acc[m][n][j]);
      }
  }
}

// out[b][o] = sum_ks part[ks][b][o] + sum_e c[b,e]*bias[e][o]
__global__ void reduce_bias_kernel(const unsigned short* __restrict__ part,
                                   const float* __restrict__ coeffs,
                                   const float* __restrict__ eb,
                                   float* __restrict__ out) {
  int t = blockIdx.x * 256 + threadIdx.x;
  int b = t >> 7;
  int o4 = (t & 127) * 4;
  float4 acc = {0.f, 0.f, 0.f, 0.f};
#pragma unroll
  for (int ksl = 0; ksl < KSPLIT; ++ksl) {
    ushort4v v = *(const ushort4v*)(part + (long)ksl * B_ * O_ + (long)b * O_ + o4);
    acc.x += bf2f(v[0]); acc.y += bf2f(v[1]);
    acc.z += bf2f(v[2]); acc.w += bf2f(v[3]);
  }
  const float* cb = coeffs + b * E_;
#pragma unroll
  for (int e = 0; e < E_; ++e) {
    float c = cb[e];
    float4 bv = *(const float4*)(eb + e * O_ + o4);
    acc.x += c * bv.x; acc.y += c * bv.y; acc.z += c * bv.z; acc.w += c * bv.w;
  }
  *(float4*)(out + (long)b * O_ + o4) = acc;
}

extern "C" void kernel_launch(void* const* d_in, const int* in_sizes, int n_in,
                              void* d_out, int out_size, void* d_ws, size_t ws_size,
                              hipStream_t stream) {
  const float* x      = (const float*)d_in[0];
  const float* coeffs = (const float*)d_in[1];
  const float* W      = (const float*)d_in[2];
  const float* eb     = (const float*)d_in[3];
  float* out = (float*)d_out;

  size_t A_bytes  = (size_t)B_ * K_ * 2;   // 16 MiB
  size_t Wt_bytes = (size_t)O_ * K_ * 2;   //  8 MiB
  size_t part_bytes = (size_t)KSPLIT * B_ * O_ * 2;  // 16 MiB
  unsigned short* A    = (unsigned short*)d_ws;
  unsigned short* Wt   = (unsigned short*)((char*)d_ws + A_bytes);
  unsigned short* part = (unsigned short*)((char*)d_ws + A_bytes + Wt_bytes);
  bool use_part = ws_size >= A_bytes + Wt_bytes + part_bytes;

  prep_kernel<<<dim3(4096 + 1024), 256, 0, stream>>>(x, coeffs, W, A, Wt);
  if (use_part) {
    gemm_kernel<1><<<dim3(NTILE * KSPLIT), 256, 0, stream>>>(A, Wt, out, part);
    reduce_bias_kernel<<<dim3(B_ * O_ / 4 / 256), 256, 0, stream>>>(part, coeffs, eb, out);
  } else {
    bias_init_kernel<<<dim3(B_ * O_ / 4 / 256), 256, 0, stream>>>(coeffs, eb, out);
    gemm_kernel<0><<<dim3(NTILE * KSPLIT), 256, 0, stream>>>(A, Wt, out, part);
  }
}

// Round 3
// 30.272 us; speedup vs baseline: 1.9092x; 1.1250x over previous
//
#include <hip/hip_runtime.h>

#define B_  1024
#define I_  512
#define O_  512
#define E_  16
#define K_  8192   // E_*I_ (W flattened as [8192][512] row-major)

#define BK 64
#define NSTEP (I_ / BK)   // 8 K-steps of the per-expert GEMM (K = I_ = 512)
#define NWG  (E_ * (B_ / 128) * (O_ / 128))   // 16 * 8 * 4 = 512 blocks

typedef __attribute__((ext_vector_type(8))) short short8;
typedef __attribute__((ext_vector_type(8))) unsigned short ushort8;
typedef __attribute__((ext_vector_type(4))) unsigned short ushort4v;
typedef __attribute__((ext_vector_type(4))) float f32x4;

__device__ __forceinline__ unsigned short f2bf(float f) {
  union { float f; unsigned u; } v; v.f = f;
  unsigned r = v.u + 0x7fffu + ((v.u >> 16) & 1u);
  return (unsigned short)(r >> 16);
}
__device__ __forceinline__ float bf2f(unsigned short h) {
  union { unsigned u; float f; } v; v.u = ((unsigned)h) << 16;
  return v.f;
}

__device__ __forceinline__ void gload_lds16(const unsigned short* g, unsigned short* l) {
  __builtin_amdgcn_global_load_lds(
      (const __attribute__((address_space(1))) void*)g,
      (__attribute__((address_space(3))) void*)l, 16, 0, 0);
}

// Fused prep: blocks [0,256) cast x -> bf16; blocks [256,1280) transpose
// W [8192][512] fp32 -> Wt [512(o)][8192(k=e*512+i)] bf16 via LDS 64x64 tiles.
__global__ void prep_kernel(const float* __restrict__ x,
                            const float* __restrict__ W,
                            unsigned short* __restrict__ xb,
                            unsigned short* __restrict__ Wt) {
  __shared__ unsigned short tile[64][65];
  if (blockIdx.x < 256) {
    int base = (blockIdx.x * 256 + threadIdx.x) * 8;
    const float4* xp = (const float4*)(x + base);
    float4 v0 = xp[0], v1 = xp[1];
    ushort8 r;
    r[0] = f2bf(v0.x); r[1] = f2bf(v0.y); r[2] = f2bf(v0.z); r[3] = f2bf(v0.w);
    r[4] = f2bf(v1.x); r[5] = f2bf(v1.y); r[6] = f2bf(v1.z); r[7] = f2bf(v1.w);
    *(ushort8*)(xb + base) = r;
  } else {
    int bw = blockIdx.x - 256;
    int kt = (bw & 127) << 6;   // along k (8192/64 = 128)
    int nt = (bw >> 7) << 6;    // along o (512/64 = 8)
    int t = threadIdx.x;
#pragma unroll
    for (int it = 0; it < 16; ++it) {
      int idx = it * 256 + t;
      int r = idx >> 6, c = idx & 63;
      tile[r][c] = f2bf(W[(long)(kt + r) * O_ + nt + c]);
    }
    __syncthreads();
#pragma unroll
    for (int it = 0; it < 2; ++it) {
      int idx = it * 256 + t;
      int r2 = idx >> 3;            // o-row within tile
      int c2 = (idx & 7) * 8;       // k base within tile
      ushort8 v;
#pragma unroll
      for (int j = 0; j < 8; ++j) v[j] = tile[c2 + j][r2];
      *(ushort8*)(Wt + (long)(nt + r2) * K_ + kt + c2) = v;
    }
  }
}

// fallback-mode bias init (atomic path)
__global__ void bias_init_kernel(const float* __restrict__ coeffs,
                                 const float* __restrict__ eb,
                                 float* __restrict__ out) {
  int t = blockIdx.x * 256 + threadIdx.x;
  int b = t >> 7;
  int o4 = (t & 127) * 4;
  const float* cb = coeffs + b * E_;
  float4 acc = {0.f, 0.f, 0.f, 0.f};
#pragma unroll
  for (int e = 0; e < E_; ++e) {
    float c = cb[e];
    float4 bv = *(const float4*)(eb + e * O_ + o4);
    acc.x += c * bv.x; acc.y += c * bv.y; acc.z += c * bv.z; acc.w += c * bv.w;
  }
  *(float4*)(out + b * O_ + o4) = acc;
}

// Per-expert GEMM: P[e][1024][512] = xb[1024][512] @ Wt(e-slice)^T.
// 128x128 tile, BK=64, double-buffered LDS, 2-phase pipeline, T2 XOR-swizzle
// (pre-swizzled global source + swizzled ds_read), bijective XCD swizzle.
template <int USE_PART>
__global__ __launch_bounds__(256) void gemm_kernel(
    const unsigned short* __restrict__ xb,
    const unsigned short* __restrict__ Wt,
    const float* __restrict__ coeffs,
    float* __restrict__ out,
    unsigned short* __restrict__ part) {
  __shared__ unsigned short As[2][128 * 64];
  __shared__ unsigned short Bs[2][128 * 64];
  // XCD-aware bijective swizzle: nwg=512, 512%8==0 -> swz=(bx%8)*64+bx/8.
  // XCD x then owns experts {2x,2x+1}: Wt slice (1MB) + xb (1MB) L2-resident.
  int bx = blockIdx.x;
  int swz = (bx & 7) * (NWG / 8) + (bx >> 3);
  int e = swz >> 5;
  int tile = swz & 31;
  int tm = tile >> 2, tn = tile & 3;
  int brow = tm * 128, bcol = tn * 128;

  int tid = threadIdx.x;
  int lane = tid & 63, wave = tid >> 6;
  int wr = wave >> 1, wc = wave & 1;

  f32x4 acc[4][4];
#pragma unroll
  for (int m = 0; m < 4; ++m)
#pragma unroll
    for (int n = 0; n < 4; ++n) acc[m][n] = (f32x4){0.f, 0.f, 0.f, 0.f};

  // staging: row-within-chunk = lane>>3, 16B piece j = lane&7.
  // Pre-swizzle k so LDS holds elem k at byte (k*2 ^ ((row&7)<<4)).
  int lr8 = lane >> 3;
  int jj = lane & 7;
  int ksrc = (jj ^ lr8) * 8;
  const unsigned short* gA = xb + (long)(brow + lr8) * I_ + ksrc;
  const unsigned short* gB = Wt + (long)(bcol + lr8) * K_ + e * I_ + ksrc;

  auto STAGE = [&](int buf, int s) {
    long kof = (long)s * BK;
#pragma unroll
    for (int i = 0; i < 4; ++i) {
      int chunk = i * 4 + wave;  // wave-uniform LDS base
      gload_lds16(gA + (long)chunk * 8 * I_ + kof, &As[buf][chunk * 512]);
      gload_lds16(gB + (long)chunk * 8 * K_ + kof, &Bs[buf][chunk * 512]);
    }
  };

  auto COMPUTE = [&](int buf) {
#pragma unroll
    for (int kk = 0; kk < 2; ++kk) {
      int kbyte = kk * 64 + (lane >> 4) * 16;  // byte offset of 8 bf16 along K
      short8 af[4], bfr[4];
#pragma unroll
      for (int m = 0; m < 4; ++m) {
        int r = wr * 64 + m * 16 + (lane & 15);
        int off = r * 64 + ((kbyte ^ ((r & 7) << 4)) >> 1);
        af[m] = *(const short8*)(&As[buf][off]);
      }
#pragma unroll
      for (int n = 0; n < 4; ++n) {
        int r = wc * 64 + n * 16 + (lane & 15);
        int off = r * 64 + ((kbyte ^ ((r & 7) << 4)) >> 1);
        bfr[n] = *(const short8*)(&Bs[buf][off]);
      }
#pragma unroll
      for (int m = 0; m < 4; ++m)
#pragma unroll
        for (int n = 0; n < 4; ++n)
          acc[m][n] = __builtin_amdgcn_mfma_f32_16x16x32_bf16(af[m], bfr[n], acc[m][n], 0, 0, 0);
    }
  };

  STAGE(0, 0);
  __syncthreads();
#pragma unroll
  for (int s = 0; s < NSTEP; ++s) {
    if (s + 1 < NSTEP) STAGE((s + 1) & 1, s + 1);  // prefetch BEFORE compute
    COMPUTE(s & 1);
    __syncthreads();
  }

  // C/D layout: col = lane&15, row = (lane>>4)*4 + reg
  int crow = wr * 64 + (lane >> 4) * 4;
  int ccol = wc * 64 + (lane & 15);
  if (USE_PART) {
    unsigned short* pb = part + (long)e * B_ * O_;
#pragma unroll
    for (int m = 0; m < 4; ++m)
#pragma unroll
      for (int n = 0; n < 4; ++n) {
        long rbase = (long)(brow + crow + m * 16) * O_ + bcol + ccol + n * 16;
#pragma unroll
        for (int j = 0; j < 4; ++j)
          pb[rbase + (long)j * O_] = f2bf(acc[m][n][j]);
      }
  } else {
    // atomic fallback: weight by c[row,e] here
#pragma unroll
    for (int m = 0; m < 4; ++m)
#pragma unroll
      for (int n = 0; n < 4; ++n) {
#pragma unroll
        for (int j = 0; j < 4; ++j) {
          int row = brow + crow + m * 16 + j;
          float c = coeffs[row * E_ + e];
          atomicAdd(out + (long)row * O_ + bcol + ccol + n * 16, c * acc[m][n][j]);
        }
      }
  }
}

// out[b][o] = sum_e c[b,e] * P[e][b][o] + sum_e c[b,e] * bias[e][o]
__global__ void combine_kernel(const unsigned short* __restrict__ part,
                               const float* __restrict__ coeffs,
                               const float* __restrict__ eb,
                               float* __restrict__ out) {
  int t = blockIdx.x * 256 + threadIdx.x;
  int b = t >> 7;
  int o4 = (t & 127) * 4;
  const float* cb = coeffs + b * E_;
  float4 acc = {0.f, 0.f, 0.f, 0.f};
#pragma unroll
  for (int e = 0; e < E_; ++e) {
    float c = cb[e];
    ushort4v v = *(const ushort4v*)(part + (long)e * B_ * O_ + (long)b * O_ + o4);
    acc.x += c * bf2f(v[0]); acc.y += c * bf2f(v[1]);
    acc.z += c * bf2f(v[2]); acc.w += c * bf2f(v[3]);
    float4 bv = *(const float4*)(eb + e * O_ + o4);
    acc.x += c * bv.x; acc.y += c * bv.y; acc.z += c * bv.z; acc.w += c * bv.w;
  }
  *(float4*)(out + (long)b * O_ + o4) = acc;
}

extern "C" void kernel_launch(void* const* d_in, const int* in_sizes, int n_in,
                              void* d_out, int out_size, void* d_ws, size_t ws_size,
                              hipStream_t stream) {
  const float* x      = (const float*)d_in[0];
  const float* coeffs = (const float*)d_in[1];
  const float* W      = (const float*)d_in[2];
  const float* eb     = (const float*)d_in[3];
  float* out = (float*)d_out;

  size_t xb_bytes   = (size_t)B_ * I_ * 2;        //  1 MiB
  size_t Wt_bytes   = (size_t)O_ * K_ * 2;        //  8 MiB
  size_t part_bytes = (size_t)E_ * B_ * O_ * 2;   // 16 MiB
  unsigned short* xb   = (unsigned short*)d_ws;
  unsigned short* Wt   = (unsigned short*)((char*)d_ws + xb_bytes);
  unsigned short* part = (unsigned short*)((char*)d_ws + xb_bytes + Wt_bytes);
  bool use_part = ws_size >= xb_bytes + Wt_bytes + part_bytes;

  prep_kernel<<<dim3(256 + 1024), 256, 0, stream>>>(x, W, xb, Wt);
  if (use_part) {
    gemm_kernel<1><<<dim3(NWG), 256, 0, stream>>>(xb, Wt, coeffs, out, part);
    combine_kernel<<<dim3(B_ * O_ / 4 / 256), 256, 0, stream>>>(part, coeffs, eb, out);
  } else {
    bias_init_kernel<<<dim3(B_ * O_ / 4 / 256), 256, 0, stream>>>(coeffs, eb, out);
    gemm_kernel<0><<<dim3(NWG), 256, 0, stream>>>(xb, Wt, coeffs, out, part);
  }
}